// Round 4
// baseline (3231.931 us; speedup 1.0000x reference)
//
#include <hip/hip_runtime.h>
#include <math.h>

// Poincare fully-connected (hypll / Shimizu et al.), c = 1.
// B=1048576, IN=64, OUT=64, all fp32.
//
// R4 design: block = 256 = 4 waves, wave = 64 rows, lane = row.
// Each lane computes ALL 64 outputs of its row -> sum(w^2) fully in-lane,
// no cross-wave reduction, no barriers after staging.
// zT + per-o constants staged in LDS once per block; dot loop reads z as
// wave-uniform ds_read_b128 broadcasts (immediate offsets, 4-in-flight chunks
// to bound register pressure). wv[64] statically indexed (o-loop fully
// unrolled). Output transposed through a per-wave [64][20] LDS chunk buffer
// (80B rows: 16B-aligned, bank-quad-uniform) reused 4x -> 64B-coalesced
// float4 stores. LDS ~37KB; VGPR ~165 with __launch_bounds__(256,3).

__global__ void hl_prep(const float* __restrict__ z, const float* __restrict__ bias,
                        float* __restrict__ ws) {
    const int o = threadIdx.x;  // 0..63
    float n2 = 0.f;
    #pragma unroll 8
    for (int k = 0; k < 64; ++k) {
        float v = z[k * 64 + o];
        ws[o * 64 + k] = v;            // zT[o][k]
        n2 = fmaf(v, v, n2);
    }
    const float zn = fmaxf(sqrtf(n2), 1e-15f);
    const float t = 2.f * bias[o];     // 2*sqrt(c)*bias, c=1
    const float e = expf(t);
    const float ei = 1.f / e;
    float4 c;
    c.x = 0.5f * (e + ei) / zn;        // K1 = cosh(2b)/zn
    c.y = 0.5f * (e - ei);             // K2 = sinh(2b)
    c.z = 2.f * zn;                    // K4 = 2*zn
    c.w = 0.f;
    reinterpret_cast<float4*>(ws + 4096)[o] = c;
}

template <bool WS>
__global__ __launch_bounds__(256, 3)
void hl_main(const float* __restrict__ x, const float* __restrict__ z,
             const float* __restrict__ bias, const float* __restrict__ ws,
             float* __restrict__ out) {
    __shared__ float  zt[64 * 64];     // 16 KB zT[o][k] (uniform broadcast reads)
    __shared__ float4 kc[64];          // 1 KB per-o constants
    __shared__ float  wt[4][64 * 20];  // 20 KB per-wave transpose chunk buffers

    const int tid  = threadIdx.x;
    const int wave = tid >> 6;
    const int lane = tid & 63;         // = row within wave tile

    // ---- issue own x row loads early (64 floats = 16 float4) ----
    const long row0 = (long)blockIdx.x * 256 + wave * 64;
    const float* __restrict__ xrow = x + (row0 + lane) * 64;
    float xs[64];
    #pragma unroll
    for (int i = 0; i < 16; ++i) {
        float4 f = reinterpret_cast<const float4*>(xrow)[i];
        xs[4*i+0] = f.x; xs[4*i+1] = f.y; xs[4*i+2] = f.z; xs[4*i+3] = f.w;
    }

    // ---- stage zT + consts into LDS (once per block) ----
    if (WS) {
        const float4* __restrict__ s4 = reinterpret_cast<const float4*>(ws);
        float4* zt4 = reinterpret_cast<float4*>(zt);
        #pragma unroll
        for (int t = 0; t < 4; ++t) zt4[t * 256 + tid] = s4[t * 256 + tid];
        if (tid < 64) kc[tid] = reinterpret_cast<const float4*>(ws + 4096)[tid];
    } else {
        if (tid < 64) {
            const int o = tid;
            float n2 = 0.f;
            for (int k = 0; k < 64; ++k) {
                float v = z[k * 64 + o];
                zt[o * 64 + k] = v;
                n2 = fmaf(v, v, n2);
            }
            const float zn = fmaxf(__builtin_amdgcn_sqrtf(n2), 1e-15f);
            const float e  = __builtin_amdgcn_exp2f(2.f * bias[o] * 1.4426950408889634f);
            const float ei = __builtin_amdgcn_rcpf(e);
            float4 c;
            c.x = 0.5f * (e + ei) * __builtin_amdgcn_rcpf(zn);
            c.y = 0.5f * (e - ei);
            c.z = 2.f * zn;
            c.w = 0.f;
            kc[o] = c;
        }
    }

    // ---- ||x||^2, lambda (in-lane) ----
    float n0 = 0.f, n1 = 0.f, n2 = 0.f, n3 = 0.f;
    #pragma unroll
    for (int j = 0; j < 16; ++j) {
        n0 = fmaf(xs[4*j+0], xs[4*j+0], n0);
        n1 = fmaf(xs[4*j+1], xs[4*j+1], n1);
        n2 = fmaf(xs[4*j+2], xs[4*j+2], n2);
        n3 = fmaf(xs[4*j+3], xs[4*j+3], n3);
    }
    const float nx2 = (n0 + n1) + (n2 + n3);
    const float lam = 2.f * __builtin_amdgcn_rcpf(1.f - nx2);   // ||x|| <= 0.9

    __syncthreads();

    // ---- all 64 outputs for this lane's row; w kept in regs (static idx) ----
    float wv[64];
    float sw2 = 0.f;
    const float4* __restrict__ ztp = reinterpret_cast<const float4*>(zt);
    #pragma unroll
    for (int o = 0; o < 64; ++o) {
        float a0 = 0.f, a1 = 0.f, a2 = 0.f, a3 = 0.f;
        // 4 chunks of (4 x ds_read_b128 + 16 FMA): bounds in-flight regs
        #pragma unroll
        for (int q4 = 0; q4 < 4; ++q4) {
            float4 z0 = ztp[o * 16 + q4 * 4 + 0];
            float4 z1 = ztp[o * 16 + q4 * 4 + 1];
            float4 z2 = ztp[o * 16 + q4 * 4 + 2];
            float4 z3 = ztp[o * 16 + q4 * 4 + 3];
            const int k = q4 * 16;
            a0 = fmaf(xs[k+ 0], z0.x, a0); a1 = fmaf(xs[k+ 1], z0.y, a1);
            a2 = fmaf(xs[k+ 2], z0.z, a2); a3 = fmaf(xs[k+ 3], z0.w, a3);
            a0 = fmaf(xs[k+ 4], z1.x, a0); a1 = fmaf(xs[k+ 5], z1.y, a1);
            a2 = fmaf(xs[k+ 6], z1.z, a2); a3 = fmaf(xs[k+ 7], z1.w, a3);
            a0 = fmaf(xs[k+ 8], z2.x, a0); a1 = fmaf(xs[k+ 9], z2.y, a1);
            a2 = fmaf(xs[k+10], z2.z, a2); a3 = fmaf(xs[k+11], z2.w, a3);
            a0 = fmaf(xs[k+12], z3.x, a0); a1 = fmaf(xs[k+13], z3.y, a1);
            a2 = fmaf(xs[k+14], z3.z, a2); a3 = fmaf(xs[k+15], z3.w, a3);
        }
        const float4 c = kc[o];
        const float xz = (a0 + a1) + (a2 + a3);
        // u = lam*(xz*K1 - K2) + K2
        const float u  = fmaf(lam, fmaf(xz, c.x, -c.y), c.y);
        const float au = fabsf(u);
        // asinh/sinh fused: t = |u|+sqrt(u^2+1); e^|v| = exp2(K4*log2(t))
        const float sq = __builtin_amdgcn_sqrtf(fmaf(au, au, 1.f));
        const float lg = __builtin_amdgcn_logf(au + sq);      // log2
        const float e  = __builtin_amdgcn_exp2f(c.z * lg);    // 2^x
        const float ei = __builtin_amdgcn_rcpf(e);
        float w = fmaf(0.5f, e, -0.5f * ei);                  // sinh(|v|)
        wv[o] = copysignf(w, u);
        sw2 = fmaf(w, w, sw2);
    }

    const float scale = __builtin_amdgcn_rcpf(1.f + __builtin_amdgcn_sqrtf(1.f + sw2));

    // ---- transpose+store in 4 chunks of 16 o's via per-wave LDS buffer ----
    // wt row stride 20 floats (80 B): 16B-aligned for b128, bank-quad uniform.
    float* __restrict__ wt_w = wt[wave];
    float* __restrict__ obase = out + row0 * 64;
    #pragma unroll
    for (int cch = 0; cch < 4; ++cch) {
        #pragma unroll
        for (int j4 = 0; j4 < 4; ++j4) {
            float4 v;
            v.x = wv[cch*16 + j4*4 + 0] * scale;
            v.y = wv[cch*16 + j4*4 + 1] * scale;
            v.z = wv[cch*16 + j4*4 + 2] * scale;
            v.w = wv[cch*16 + j4*4 + 3] * scale;
            *reinterpret_cast<float4*>(wt_w + lane * 20 + j4 * 4) = v;
        }
        // per-wave in-order DS: reads of this chunk follow writes; next
        // chunk's writes can't pass these reads (alias-ordered).
        #pragma unroll
        for (int s = 0; s < 4; ++s) {
            const int idx = s * 64 + lane;     // float4 slot in 64x16 chunk
            const int row = idx >> 2;
            const int o4  = idx & 3;
            float4 v = *reinterpret_cast<const float4*>(wt_w + row * 20 + o4 * 4);
            *reinterpret_cast<float4*>(obase + (long)row * 64 + cch * 16 + o4 * 4) = v;
        }
    }
}

extern "C" void kernel_launch(void* const* d_in, const int* in_sizes, int n_in,
                              void* d_out, int out_size, void* d_ws, size_t ws_size,
                              hipStream_t stream) {
    const float* x    = (const float*)d_in[0];
    const float* z    = (const float*)d_in[1];
    const float* bias = (const float*)d_in[2];
    float* out = (float*)d_out;
    float* ws  = (float*)d_ws;

    const long rows   = (long)in_sizes[0] / 64;   // 1048576
    const int  blocks = (int)(rows / 256);        // 4 waves * 64 rows per block

    if (ws_size >= (size_t)(4096 + 256) * sizeof(float)) {
        hl_prep<<<1, 64, 0, stream>>>(z, bias, ws);
        hl_main<true><<<blocks, 256, 0, stream>>>(x, z, bias, ws, out);
    } else {
        hl_main<false><<<blocks, 256, 0, stream>>>(x, z, bias, nullptr, out);
    }
}

// Round 5
// 639.629 us; speedup vs baseline: 5.0528x; 5.0528x over previous
//
#include <hip/hip_runtime.h>
#include <math.h>

// Poincare fully-connected (hypll / Shimizu et al.), c = 1.
// B=1048576, IN=64, OUT=64, all fp32.
//
// R5 design: wave = 64 rows, lane = OUTPUT o. No LDS, no barriers, no big
// per-lane arrays:
//   - z^T column `lane` loaded once per wave into 32 v2f VGPRs; K1/K2/K4 regs.
//   - pre-pass (lane=row): row norm -> lam, distributed 1/lane, read per row
//     via v_readlane (uniform SGPR).
//   - row loop: x[r][*] is wave-UNIFORM -> s_load into SGPRs (no VGPR cost);
//     dot = 32 packed v2f FMAs; trans chain per lane; sum(w^2) via 6-round
//     __shfl_xor butterfly; store = coalesced 256B global_store_dword.
// VGPR ~100 -> 4-5 waves/SIMD; LDS 0.

typedef float v2f __attribute__((ext_vector_type(2)));

__global__ void hl_prep(const float* __restrict__ z, const float* __restrict__ bias,
                        float* __restrict__ ws) {
    const int o = threadIdx.x;  // 0..63
    float n2 = 0.f;
    #pragma unroll 8
    for (int k = 0; k < 64; ++k) {
        float v = z[k * 64 + o];
        ws[o * 64 + k] = v;            // zT[o][k]
        n2 = fmaf(v, v, n2);
    }
    const float zn = fmaxf(sqrtf(n2), 1e-15f);
    const float t = 2.f * bias[o];     // 2*sqrt(c)*bias, c=1
    const float e = expf(t);
    const float ei = 1.f / e;
    float4 c;
    c.x = 0.5f * (e + ei) / zn;        // K1 = cosh(2b)/zn
    c.y = 0.5f * (e - ei);             // K2 = sinh(2b)
    c.z = 2.f * zn;                    // K4 = 2*zn
    c.w = 0.f;
    reinterpret_cast<float4*>(ws + 4096)[o] = c;
}

template <bool WS>
__global__ __launch_bounds__(256, 4)
void hl_main(const float* __restrict__ x, const float* __restrict__ z,
             const float* __restrict__ bias, const float* __restrict__ ws,
             float* __restrict__ out) {
    const int tid  = threadIdx.x;
    const int wave = tid >> 6;
    const int lane = tid & 63;
    const long row0 = (long)blockIdx.x * 256 + wave * 64;
    const float* __restrict__ xt = x + row0 * 64;

    // ---- (1) row-norm pre-pass: lane = row ----
    float n0 = 0.f, n1 = 0.f, n2 = 0.f, n3 = 0.f;
    const float4* __restrict__ xl = reinterpret_cast<const float4*>(xt + lane * 64);
    #pragma unroll
    for (int g = 0; g < 4; ++g) {
        float4 f0 = xl[g*4+0], f1 = xl[g*4+1], f2 = xl[g*4+2], f3 = xl[g*4+3];
        n0 = fmaf(f0.x,f0.x,n0); n1 = fmaf(f0.y,f0.y,n1); n2 = fmaf(f0.z,f0.z,n2); n3 = fmaf(f0.w,f0.w,n3);
        n0 = fmaf(f1.x,f1.x,n0); n1 = fmaf(f1.y,f1.y,n1); n2 = fmaf(f1.z,f1.z,n2); n3 = fmaf(f1.w,f1.w,n3);
        n0 = fmaf(f2.x,f2.x,n0); n1 = fmaf(f2.y,f2.y,n1); n2 = fmaf(f2.z,f2.z,n2); n3 = fmaf(f2.w,f2.w,n3);
        n0 = fmaf(f3.x,f3.x,n0); n1 = fmaf(f3.y,f3.y,n1); n2 = fmaf(f3.z,f3.z,n2); n3 = fmaf(f3.w,f3.w,n3);
    }
    const float nx2  = (n0 + n1) + (n2 + n3);
    const float lamv = 2.f * __builtin_amdgcn_rcpf(1.f - nx2);   // ||x|| <= 0.9

    // ---- (2) z^T column `lane` + per-o constants (once per wave) ----
    v2f zt[32];
    float K1, K2, K4;
    if (WS) {
        const v2f* __restrict__ zc = reinterpret_cast<const v2f*>(ws + lane * 64);
        #pragma unroll
        for (int q = 0; q < 32; ++q) zt[q] = zc[q];
        const float4 c = reinterpret_cast<const float4*>(ws + 4096)[lane];
        K1 = c.x; K2 = c.y; K4 = c.z;
    } else {
        float q2 = 0.f;
        float* ztf = reinterpret_cast<float*>(zt);
        #pragma unroll 8
        for (int k = 0; k < 64; ++k) {
            float v = z[k * 64 + lane];
            ztf[k] = v;
            q2 = fmaf(v, v, q2);
        }
        const float zn = fmaxf(__builtin_amdgcn_sqrtf(q2), 1e-15f);
        const float e  = __builtin_amdgcn_exp2f(2.f * bias[lane] * 1.4426950408889634f);
        const float ei = __builtin_amdgcn_rcpf(e);
        K1 = 0.5f * (e + ei) * __builtin_amdgcn_rcpf(zn);
        K2 = 0.5f * (e - ei);
        K4 = 2.f * zn;
    }

    // ---- (3) row loop: x row is wave-uniform -> SGPRs ----
    float* __restrict__ ot = out + row0 * 64;
    #pragma unroll 2
    for (int r = 0; r < 64; ++r) {
        const float lam = __uint_as_float(
            __builtin_amdgcn_readlane(__float_as_uint(lamv), r));
        const v2f* __restrict__ xr = reinterpret_cast<const v2f*>(xt + r * 64);
        v2f a0 = {0.f, 0.f}, a1 = {0.f, 0.f};
        #pragma unroll
        for (int q = 0; q < 16; ++q) {
            a0 = zt[2*q+0] * xr[2*q+0] + a0;    // v_pk_fma_f32, src = SGPR pair
            a1 = zt[2*q+1] * xr[2*q+1] + a1;
        }
        const float xz = (a0.x + a1.x) + (a0.y + a1.y);
        // u = lam*(xz*K1 - K2) + K2
        const float u  = fmaf(lam, fmaf(xz, K1, -K2), K2);
        const float au = fabsf(u);
        // asinh/sinh fused: t = |u|+sqrt(u^2+1); e^|v| = exp2(K4*log2(t))
        const float sq = __builtin_amdgcn_sqrtf(fmaf(au, au, 1.f));
        const float lg = __builtin_amdgcn_logf(au + sq);      // log2
        const float e  = __builtin_amdgcn_exp2f(K4 * lg);     // 2^x
        const float ei = __builtin_amdgcn_rcpf(e);
        const float w  = copysignf(fmaf(0.5f, e, -0.5f * ei), u);   // sinh
        // ---- wave-wide sum(w^2): 6-round butterfly ----
        float s2 = w * w;
        s2 += __shfl_xor(s2, 1);
        s2 += __shfl_xor(s2, 2);
        s2 += __shfl_xor(s2, 4);
        s2 += __shfl_xor(s2, 8);
        s2 += __shfl_xor(s2, 16);
        s2 += __shfl_xor(s2, 32);
        const float scale = __builtin_amdgcn_rcpf(1.f + __builtin_amdgcn_sqrtf(1.f + s2));
        ot[r * 64 + lane] = w * scale;           // coalesced 256B store
    }
}

extern "C" void kernel_launch(void* const* d_in, const int* in_sizes, int n_in,
                              void* d_out, int out_size, void* d_ws, size_t ws_size,
                              hipStream_t stream) {
    const float* x    = (const float*)d_in[0];
    const float* z    = (const float*)d_in[1];
    const float* bias = (const float*)d_in[2];
    float* out = (float*)d_out;
    float* ws  = (float*)d_ws;

    const long rows   = (long)in_sizes[0] / 64;   // 1048576
    const int  blocks = (int)(rows / 256);        // 4 waves * 64 rows per block

    if (ws_size >= (size_t)(4096 + 256) * sizeof(float)) {
        hl_prep<<<1, 64, 0, stream>>>(z, bias, ws);
        hl_main<true><<<blocks, 256, 0, stream>>>(x, z, bias, ws, out);
    } else {
        hl_main<false><<<blocks, 256, 0, stream>>>(x, z, bias, nullptr, out);
    }
}